// Round 8
// baseline (68768.616 us; speedup 1.0000x reference)
//
#include <hip/hip_runtime.h>

#define LSEQ 8128
#define NB 8
#define CORR_CAP 8192
#define FLAG_R0 0

typedef __attribute__((ext_vector_type(8))) short short8;
typedef __attribute__((ext_vector_type(4))) float float4e;
typedef __attribute__((ext_vector_type(4))) int int4v;

#define MFMA16(a,b,c) __builtin_amdgcn_mfma_f32_16x16x32_bf16((a),(b),(c),0,0,0)
#define MFMAI8(a,b,c) __builtin_amdgcn_mfma_i32_16x16x64_i8((a),(b),(c),0,0,0)

// ---- workspace layout (bytes) ----
#define WS_P      4096ul
#define WS_AEE    528384ul
#define WS_VPN    536576ul      // bf16 swizzled [8128][1024]
#define WS_EIDX   17182720ul
#define WS_CORR   17444864ul    // bf16 swizzled [8192][1024]
#define WS_WQ0    34222080ul    // i8 [1024][256]
#define WS_SC0    34484224ul    // f32 [512]
#define WS_WQC    34488320ul    // i8 [1024][512]  (Wih1|Whh1 concat)
#define WS_SCC    35012608ul    // f32 [512]
#define WS_H0G    35016704ul    // i8 [8129][512 dw] = 16648192
#define WS_H1W    51664896ul    // bf16 [8129][8][256] = 33296384
// end ~85 MB

static __device__ __forceinline__ unsigned short f2bf(float f) {
  unsigned u = __float_as_uint(f);
  return (unsigned short)((u + 0x7fffu + ((u >> 16) & 1u)) >> 16);  // RNE
}
static __device__ __forceinline__ float blo(unsigned u) { return __uint_as_float(u << 16); }
static __device__ __forceinline__ float bhi(unsigned u) { return __uint_as_float(u & 0xffff0000u); }
static __device__ __forceinline__ float upk(uint2 v, int r) {
  unsigned d = (r < 2) ? v.x : v.y;
  return (r & 1) ? bhi(d) : blo(d);
}
static __device__ __forceinline__ short8 pack8f(const float* __restrict__ p) {
  short8 r;
#pragma unroll
  for (int i = 0; i < 8; ++i) r[i] = (short)f2bf(p[i]);
  return r;
}
static __device__ __forceinline__ unsigned aload(const unsigned* p) {
  return __hip_atomic_load(p, __ATOMIC_RELAXED, __HIP_MEMORY_SCOPE_AGENT);
}
static __device__ __forceinline__ void astore(unsigned* p, unsigned v) {
  __hip_atomic_store(p, v, __ATOMIC_RELAXED, __HIP_MEMORY_SCOPE_AGENT);
}
static __device__ __forceinline__ void fencev() {
  asm volatile("s_waitcnt vmcnt(0)" ::: "memory");
}
static __device__ __forceinline__ void barrier_lgkm() {
  asm volatile("s_waitcnt lgkmcnt(0)\ns_barrier" ::: "memory");
}
static __device__ __forceinline__ float sigf(float x) { return 1.f / (1.f + __expf(-x)); }
static __device__ __forceinline__ float tanhf2(float x) { return 2.f / (1.f + __expf(-2.f * x)) - 1.f; }

__global__ void k_prep_P(const float* __restrict__ Wih0, const float* __restrict__ ewW2,
                         float* __restrict__ P) {
  int idx = blockIdx.x * 256 + threadIdx.x;
  int g = idx >> 7, k = idx & 127;
  const float* wr = Wih0 + (size_t)g * 320 + 128;
  float s = 0.f;
#pragma unroll 8
  for (int j = 0; j < 64; ++j) s += wr[j] * ewW2[j * 128 + k];
  P[idx] = s;
}

__global__ void k_prep_aee(const float* __restrict__ Wih0, const float* __restrict__ ee,
                           const float* __restrict__ b1, const float* __restrict__ b2,
                           const float* __restrict__ P, float* __restrict__ aee) {
  int idx = blockIdx.x * 256 + threadIdx.x;  // < 2048
  int s = idx >> 10, g = idx & 1023;
  const float* wr = Wih0 + (size_t)g * 320;
  float a = 0.f;
#pragma unroll 8
  for (int i = 0; i < 128; ++i) a += wr[i] * ee[s * 128 + i];
#pragma unroll 8
  for (int j = 0; j < 64; ++j) a += wr[128 + j] * b2[j];
  const float* pr = P + (size_t)g * 128;
#pragma unroll 8
  for (int k = 0; k < 128; ++k) a += pr[k] * fmaxf(b1[k], 0.f);
  aee[s * 1024 + g] = a;
}

// slot s=(w,lk,G,r): g = G*256 + w*16 + lk*4 + r  (w=wave, 16 waves)
static __device__ __forceinline__ int slot2g(int s) {
  int w = s >> 6, lk = (s >> 4) & 3, G = (s >> 2) & 3, r = s & 3;
  return G * 256 + w * 16 + lk * 4 + r;
}

__global__ void k_prep_vpn(const float* __restrict__ Wih0, const float* __restrict__ nemb,
                           const float* __restrict__ aee, unsigned short* __restrict__ vpnsw) {
  __shared__ float pn[128];
  int t = blockIdx.x, tid = threadIdx.x;
  if (tid < 32) {
    float div = expf(-9.2103403719761836f * (float)(2 * tid) / 64.f);
    float ang = (float)t * div;
    pn[2 * tid] = sinf(ang);
    pn[2 * tid + 1] = cosf(ang);
  } else if (tid < 96) {
    int r = (int)((1.f + sqrtf(8.f * (float)t + 1.f)) * 0.5f);
    while (r * (r + 1) / 2 <= t) ++r;
    while (r * (r - 1) / 2 > t) --r;
    pn[64 + (tid - 32)] = nemb[r * 64 + (tid - 32)];
  }
  __syncthreads();
#pragma unroll
  for (int rr = 0; rr < 4; ++rr) {
    int slot = rr * 256 + tid;
    int g = slot2g(slot);
    const float* wr = Wih0 + (size_t)g * 320 + 192;
    float s = 0.f;
#pragma unroll 8
    for (int i = 0; i < 128; ++i) s += wr[i] * pn[i];
    vpnsw[(size_t)t * 1024 + slot] = f2bf(s + aee[g]);
  }
}

__global__ void k_prep_eidx(const float* __restrict__ xadj, int* __restrict__ eidx,
                            unsigned* __restrict__ counter) {
  int idx = blockIdx.x * 256 + threadIdx.x;
  if (idx >= NB * LSEQ) return;
  int t = idx % LSEQ;
  int e = -1;
  if (t > 0 && xadj[idx - 1] > 0.f) {
    e = (int)atomicAdd(counter, 1u);
    if (e >= CORR_CAP) e = -1;
  }
  eidx[idx] = e;
}

__global__ void k_prep_corr(const float* __restrict__ xadj, const float* __restrict__ w1,
                            const float* __restrict__ b1, const float* __restrict__ P,
                            const float* __restrict__ aee, const int* __restrict__ eidx,
                            unsigned short* __restrict__ corrsw) {
  __shared__ float rh[128];
  int bid = blockIdx.x;
  int e = eidx[bid];
  if (e < 0) return;
  int tid = threadIdx.x;
  float wt = xadj[bid - 1];
  if (tid < 128) {
    float bb = b1[tid];
    rh[tid] = fmaxf(wt * w1[tid] + bb, 0.f) - fmaxf(bb, 0.f);
  }
  __syncthreads();
#pragma unroll
  for (int rr = 0; rr < 4; ++rr) {
    int slot = rr * 256 + tid;
    int g = slot2g(slot);
    const float* pr = P + (size_t)g * 128;
    float s = 0.f;
#pragma unroll 8
    for (int k = 0; k < 128; ++k) s += pr[k] * rh[k];
    corrsw[(size_t)e * 1024 + slot] = f2bf(s + aee[1024 + g] - aee[g]);
  }
}

// i8 quantize: pid<512 -> Whh0 row-pair (K=256); else -> [Wih1|Whh1] row-pair (K=512)
__global__ void k_prep_qw(const float* __restrict__ Whh0, const float* __restrict__ Wih1,
                          const float* __restrict__ Whh1,
                          unsigned* __restrict__ q0, unsigned* __restrict__ qc,
                          float* __restrict__ d0, float* __restrict__ dc) {
  int pid = blockIdx.x, t = threadIdx.x;
  if (pid < 512) {
    int r0 = pid * 2;
    float a[4], b4[4], mx = 0.f;
#pragma unroll
    for (int i = 0; i < 4; ++i) {
      a[i] = Whh0[(size_t)r0 * 256 + t * 4 + i];
      b4[i] = Whh0[(size_t)(r0 + 1) * 256 + t * 4 + i];
      mx = fmaxf(mx, fmaxf(fabsf(a[i]), fabsf(b4[i])));
    }
#pragma unroll
    for (int d2 = 1; d2 < 64; d2 <<= 1) mx = fmaxf(mx, __shfl_xor(mx, d2));
    mx = fmaxf(mx, 1e-20f);
    float inv = 127.f / mx;
    unsigned pa = 0, pb = 0;
#pragma unroll
    for (int i = 0; i < 4; ++i) {
      int qa = (int)rintf(a[i] * inv), qb = (int)rintf(b4[i] * inv);
      pa |= ((unsigned)(qa & 255)) << (8 * i);
      pb |= ((unsigned)(qb & 255)) << (8 * i);
    }
    q0[(size_t)r0 * 64 + t] = pa;
    q0[(size_t)(r0 + 1) * 64 + t] = pb;
    if (t == 0) d0[pid] = mx / 16129.f;
  } else {
    int pr = pid - 512, r0 = pr * 2;
    float a[8], b4[8], mx = 0.f;
#pragma unroll
    for (int i = 0; i < 8; ++i) {
      int c = t * 8 + i;
      a[i] = (c < 256) ? Wih1[(size_t)r0 * 256 + c] : Whh1[(size_t)r0 * 256 + c - 256];
      b4[i] = (c < 256) ? Wih1[(size_t)(r0 + 1) * 256 + c] : Whh1[(size_t)(r0 + 1) * 256 + c - 256];
      mx = fmaxf(mx, fmaxf(fabsf(a[i]), fabsf(b4[i])));
    }
#pragma unroll
    for (int d2 = 1; d2 < 64; d2 <<= 1) mx = fmaxf(mx, __shfl_xor(mx, d2));
    mx = fmaxf(mx, 1e-20f);
    float inv = 127.f / mx;
    unsigned pa0 = 0, pa1 = 0, pb0 = 0, pb1 = 0;
#pragma unroll
    for (int i = 0; i < 4; ++i) {
      pa0 |= ((unsigned)(((int)rintf(a[i] * inv)) & 255)) << (8 * i);
      pa1 |= ((unsigned)(((int)rintf(a[4 + i] * inv)) & 255)) << (8 * i);
      pb0 |= ((unsigned)(((int)rintf(b4[i] * inv)) & 255)) << (8 * i);
      pb1 |= ((unsigned)(((int)rintf(b4[4 + i] * inv)) & 255)) << (8 * i);
    }
    qc[(size_t)r0 * 128 + t * 2] = pa0;
    qc[(size_t)r0 * 128 + t * 2 + 1] = pa1;
    qc[(size_t)(r0 + 1) * 128 + t * 2] = pb0;
    qc[(size_t)(r0 + 1) * 128 + t * 2 + 1] = pb1;
    if (t == 0) dc[pr] = mx / 16129.f;
  }
}

// ======== 2-WG persistent LSTM: WG0 = layer0 (free-running), WG1 = layer1 ========
static __device__ __forceinline__ void recur0(
    const unsigned* __restrict__ wq0, const float* __restrict__ sc0,
    const unsigned* __restrict__ vpn32, const int* __restrict__ eidx,
    const unsigned* __restrict__ cor32, const float* __restrict__ inith,
    const float* __restrict__ initc, unsigned* flags, unsigned* h0g,
    unsigned* hTd, int tid) {
  const int w = tid >> 6, l = tid & 63, lm = l & 15, lk = l >> 4, b = lm & 7;
  unsigned char* hTb = (unsigned char*)hTd;

  for (int i = tid; i < 1088; i += 1024) hTd[i] = 0;
  __syncthreads();
  if (tid < 512) {
    int b0 = tid >> 6, idx = tid & 63;
    unsigned pk = 0;
#pragma unroll
    for (int i = 0; i < 4; ++i) {
      int q = (int)rintf(inith[(idx * 4 + i) & 127] * 127.f);
      pk |= ((unsigned)(q & 255)) << (8 * i);
    }
    hTd[b0 * 68 + idx] = pk;
  }
  float c_[4];
#pragma unroll
  for (int r = 0; r < 4; ++r) c_[r] = initc[(w * 16 + lk * 4 + r) & 127];

  int4v wq[4][4];
  float sc[4][2];
#pragma unroll
  for (int G = 0; G < 4; ++G) {
    int g = G * 256 + w * 16 + lm;
#pragma unroll
    for (int f = 0; f < 4; ++f)
      wq[G][f] = *(const int4v*)(wq0 + (size_t)g * 64 + f * 16 + lk * 4);
#pragma unroll
    for (int rp = 0; rp < 2; ++rp) sc[G][rp] = sc0[G * 128 + w * 8 + lk * 2 + rp];
  }
  __syncthreads();

  for (int t = 0; t < LSEQ; ++t) {
    const int vbase = t * 512 + w * 32 + lk * 8;
    uint2 vv[4], cv[4];
#pragma unroll
    for (int G = 0; G < 4; ++G) vv[G] = *(const uint2*)(vpn32 + vbase + G * 2);
    int e = eidx[b * LSEQ + t];
#pragma unroll
    for (int G = 0; G < 4; ++G) cv[G] = make_uint2(0u, 0u);
    if (e >= 0) {
      const unsigned* cp = cor32 + (size_t)e * 512 + w * 32 + lk * 8;
#pragma unroll
      for (int G = 0; G < 4; ++G) cv[G] = *(const uint2*)(cp + G * 2);
    }
    const int cur = t & 1, nxt = 1 - cur;
    int4v bfr[4];
#pragma unroll
    for (int f = 0; f < 4; ++f)
      bfr[f] = *(const int4v*)&hTb[cur * 2176 + b * 272 + f * 64 + lk * 16];
    int4v acc[4];
#pragma unroll
    for (int G = 0; G < 4; ++G) {
      acc[G] = (int4v){0, 0, 0, 0};
#pragma unroll
      for (int f = 0; f < 4; ++f) acc[G] = MFMAI8(wq[G][f], bfr[f], acc[G]);
    }
    unsigned pk = 0;
#pragma unroll
    for (int r = 0; r < 4; ++r) {
      const int rp = r >> 1;
      float g0 = (float)acc[0][r] * sc[0][rp] + upk(vv[0], r) + upk(cv[0], r);
      float g1 = (float)acc[1][r] * sc[1][rp] + upk(vv[1], r) + upk(cv[1], r);
      float g2 = (float)acc[2][r] * sc[2][rp] + upk(vv[2], r) + upk(cv[2], r);
      float g3 = (float)acc[3][r] * sc[3][rp] + upk(vv[3], r) + upk(cv[3], r);
      float cn = sigf(g1) * c_[r] + sigf(g0) * tanhf2(g2);
      c_[r] = cn;
      float h = sigf(g3) * tanhf2(cn);
      int q = (int)rintf(h * 127.f);
      pk |= ((unsigned)(q & 255)) << (8 * r);
    }
    if (lm < 8) {
      hTd[nxt * 544 + b * 68 + w * 4 + lk] = pk;
      astore(h0g + (size_t)(t + 1) * 512 + w * 32 + b * 4 + lk, pk);
    }
    if ((t & 7) == 7) {
      __syncthreads();  // drains vmcnt across all waves
      if (tid == 0) astore(flags + FLAG_R0, (unsigned)(t + 1));
    } else {
      barrier_lgkm();
    }
  }
}

static __device__ __forceinline__ void recur1(
    const unsigned* __restrict__ wqc, const float* __restrict__ scc,
    const unsigned* __restrict__ h0g, const float* __restrict__ inith,
    const float* __restrict__ initc, unsigned* flags, unsigned* h1w,
    unsigned* hc, int tid) {
  const int w = tid >> 6, l = tid & 63, lm = l & 15, lk = l >> 4, b = lm & 7;
  unsigned char* hcb = (unsigned char*)hc;
  unsigned budget = 100000000u;

  float c_[4];
#pragma unroll
  for (int r = 0; r < 4; ++r) c_[r] = initc[(w * 16 + lk * 4 + r) & 127];

  int4v wq[4][8];
  float sc[4][2];
#pragma unroll
  for (int G = 0; G < 4; ++G) {
    int g = G * 256 + w * 16 + lm;
#pragma unroll
    for (int f = 0; f < 8; ++f)
      wq[G][f] = *(const int4v*)(wqc + (size_t)g * 128 + f * 16 + lk * 4);
#pragma unroll
    for (int rp = 0; rp < 2; ++rp) sc[G][rp] = scc[G * 128 + w * 8 + lk * 2 + rp];
  }

  // prologue: stage h0(slot1) + h1(0)=inith into buf0
  unsigned Fc = 0;
  while (Fc < 1u) {
    Fc = aload(flags + FLAG_R0);
    if (--budget == 0) break;
    __builtin_amdgcn_s_sleep(2);
  }
  const int d = tid, w2 = d >> 5, b2 = (d >> 2) & 7, lk2 = d & 3;
  if (tid < 512) {
    unsigned pf0 = aload(h0g + 512 + d);
    fencev();
    hc[b2 * 136 + w2 * 4 + lk2] = pf0;
    int b0 = tid >> 6, idx = tid & 63;
    unsigned pk = 0;
#pragma unroll
    for (int i = 0; i < 4; ++i) {
      int q = (int)rintf(inith[(idx * 4 + i) & 127] * 127.f);
      pk |= ((unsigned)(q & 255)) << (8 * i);
    }
    hc[b0 * 136 + 64 + idx] = pk;
  }
  __syncthreads();

  for (int t = 0; t < LSEQ; ++t) {
    const int cur = t & 1, nxt = 1 - cur;
    unsigned pf = 0;
    const bool haspf = (t + 1 < LSEQ);
    if (haspf) {
      while (Fc < (unsigned)(t + 2)) {
        Fc = aload(flags + FLAG_R0);
        if (--budget == 0) break;
        __builtin_amdgcn_s_sleep(1);
      }
      if (tid < 512) pf = aload(h0g + (size_t)(t + 2) * 512 + d);
    }
    int4v bfr[8];
#pragma unroll
    for (int f = 0; f < 8; ++f)
      bfr[f] = *(const int4v*)&hcb[cur * 4352 + b * 544 + f * 64 + lk * 16];
    int4v acc[4];
#pragma unroll
    for (int G = 0; G < 4; ++G) {
      acc[G] = (int4v){0, 0, 0, 0};
#pragma unroll
      for (int f = 0; f < 8; ++f) acc[G] = MFMAI8(wq[G][f], bfr[f], acc[G]);
    }
    fencev();  // pf arrived (overlapped with MFMAs); prev-step stores long retired
    if (haspf && tid < 512) hc[nxt * 1088 + b2 * 136 + w2 * 4 + lk2] = pf;
    unsigned pk = 0;
    float hv4[4];
#pragma unroll
    for (int r = 0; r < 4; ++r) {
      const int rp = r >> 1;
      float g0 = (float)acc[0][r] * sc[0][rp];
      float g1 = (float)acc[1][r] * sc[1][rp];
      float g2 = (float)acc[2][r] * sc[2][rp];
      float g3 = (float)acc[3][r] * sc[3][rp];
      float cn = sigf(g1) * c_[r] + sigf(g0) * tanhf2(g2);
      c_[r] = cn;
      float h = sigf(g3) * tanhf2(cn);
      hv4[r] = h;
      int q = (int)rintf(h * 127.f);
      pk |= ((unsigned)(q & 255)) << (8 * r);
    }
    if (lm < 8) {
      hc[nxt * 1088 + b * 136 + 64 + w * 4 + lk] = pk;
      uint2 hw;
      hw.x = (unsigned)f2bf(hv4[0]) | ((unsigned)f2bf(hv4[1]) << 16);
      hw.y = (unsigned)f2bf(hv4[2]) | ((unsigned)f2bf(hv4[3]) << 16);
      *(uint2*)(h1w + (size_t)(t + 1) * 1024 + b * 128 + w * 8 + lk * 2) = hw;
    }
    barrier_lgkm();
  }
}

__global__ __launch_bounds__(1024, 4) void k_lstm(
    const unsigned* __restrict__ wq0, const float* __restrict__ sc0,
    const unsigned* __restrict__ wqc, const float* __restrict__ scc,
    const unsigned* __restrict__ vpn32, const int* __restrict__ eidx,
    const unsigned* __restrict__ cor32, const float* __restrict__ inith,
    const float* __restrict__ initc, unsigned* flags, unsigned* h0g, unsigned* h1w) {
  __shared__ __align__(16) unsigned hTd[1088];   // L0 h dbuf (2*2176 B)
  __shared__ __align__(16) unsigned hc[2176];    // L1 [h0|h1] dbuf (2*4352 B)
  __shared__ char cupad[98304];                  // force 1 WG/CU
  const int tid = threadIdx.x;
  cupad[tid] = 0;
  if (blockIdx.x == 0)
    recur0(wq0, sc0, vpn32, eidx, cor32, inith, initc, flags, h0g, hTd, tid);
  else
    recur1(wqc, scc, h0g, inith, initc, flags, h1w, hc, tid);
}

// ---- heads (unchanged) ----
__global__ __launch_bounds__(256, 2) void k_heads(
    const unsigned short* __restrict__ h1u, const float* __restrict__ xadj,
    const float* __restrict__ lgW1, const float* __restrict__ lgb1,
    const float* __restrict__ lgW2, const float* __restrict__ lgb2,
    const float* __restrict__ muW1, const float* __restrict__ mub1,
    const float* __restrict__ muW2, const float* __restrict__ mub2,
    const float* __restrict__ vaW1, const float* __restrict__ vab1,
    const float* __restrict__ vaW2, const float* __restrict__ vab2,
    float* dout) {
  __shared__ float vals[4][3][64];
  const int tid = threadIdx.x;
  const int v = tid >> 6, l = tid & 63, lm = l & 15, lk = l >> 4;
  const int wid = blockIdx.x * 4 + v;
  const int m0 = wid * 64;

  short8 afr[4][8];
#pragma unroll
  for (int tt = 0; tt < 4; ++tt)
#pragma unroll
    for (int ks = 0; ks < 8; ++ks)
      afr[tt][ks] = *(const short8*)(h1u + (size_t)(m0 + tt * 16 + lm) * 256 + 2048 + ks * 32 + lk * 8);

  const float* W1s[3] = {lgW1, muW1, vaW1};
  const float* b1s[3] = {lgb1, mub1, vab1};
  const float* W2s[3] = {lgW2, muW2, vaW2};

  for (int h = 0; h < 3; ++h) {
    float accr[4][4];
#pragma unroll
    for (int tt = 0; tt < 4; ++tt)
#pragma unroll
      for (int r = 0; r < 4; ++r) accr[tt][r] = 0.f;
    const float* W1p = W1s[h];
    const float* b1p = b1s[h];
    const float* W2p = W2s[h];
    for (int nt = 0; nt < 32; ++nt) {
      float4e c0 = {0.f, 0.f, 0.f, 0.f}, c1 = c0, c2 = c0, c3 = c0;
      const float* wp = W1p + (size_t)(nt * 16 + lm) * 256;
#pragma unroll
      for (int ks = 0; ks < 8; ++ks) {
        short8 bfr = pack8f(wp + ks * 32 + lk * 8);
        c0 = MFMA16(afr[0][ks], bfr, c0);
        c1 = MFMA16(afr[1][ks], bfr, c1);
        c2 = MFMA16(afr[2][ks], bfr, c2);
        c3 = MFMA16(afr[3][ks], bfr, c3);
      }
      float bias = b1p[nt * 16 + lm], w2v = W2p[nt * 16 + lm];
#pragma unroll
      for (int r = 0; r < 4; ++r) {
        accr[0][r] += fmaxf(c0[r] + bias, 0.f) * w2v;
        accr[1][r] += fmaxf(c1[r] + bias, 0.f) * w2v;
        accr[2][r] += fmaxf(c2[r] + bias, 0.f) * w2v;
        accr[3][r] += fmaxf(c3[r] + bias, 0.f) * w2v;
      }
    }
#pragma unroll
    for (int tt = 0; tt < 4; ++tt)
#pragma unroll
      for (int r = 0; r < 4; ++r) {
        float a2 = accr[tt][r];
        a2 += __shfl_xor(a2, 1);
        a2 += __shfl_xor(a2, 2);
        a2 += __shfl_xor(a2, 4);
        a2 += __shfl_xor(a2, 8);
        if (lm == 0) vals[v][h][tt * 16 + lk * 4 + r] = a2;
      }
  }
  __syncthreads();
  {
    int m = m0 + l;
    int tq = m >> 3, b = m & 7;
    float z = vals[v][0][l] + lgb2[0];
    float mu = vals[v][1][l] + mub2[0];
    float lv = vals[v][2][l] + vab2[0];
    float x = xadj[(size_t)b * LSEQ + tq];
    float xt = (x > 0.f) ? 1.f : 0.f;
    float lr = fmaxf(z, 0.f) - z * xt + log1pf(expf(-fabsf(z)));
    float lw = 0.f;
    if (x > 0.f) {
      float sm = (x > 20.f) ? x : logf(expm1f(fminf(x, 20.f)));
      float d = mu - sm;
      lw = 0.5f * (lv + d * d * expf(-lv));
    }
#pragma unroll
    for (int d2 = 1; d2 < 64; d2 <<= 1) {
      lr += __shfl_xor(lr, d2);
      lw += __shfl_xor(lw, d2);
    }
    if (l == 0) {
      atomicAdd(dout + 0, lr * (1.f / 1024.f));
      atomicAdd(dout + 1, lw * (1.f / 1024.f));
    }
  }
}

extern "C" void kernel_launch(void* const* d_in, const int* in_sizes, int n_in,
                              void* d_out, int out_size, void* d_ws, size_t ws_size,
                              hipStream_t stream) {
  const float* x_adj = (const float*)d_in[0];
  const float* ee    = (const float*)d_in[1];
  const float* nemb  = (const float*)d_in[2];
  const float* ewW1  = (const float*)d_in[3];
  const float* ewb1  = (const float*)d_in[4];
  const float* ewW2  = (const float*)d_in[5];
  const float* ewb2  = (const float*)d_in[6];
  const float* Wih0  = (const float*)d_in[7];
  const float* Whh0  = (const float*)d_in[8];
  const float* Wih1  = (const float*)d_in[9];
  const float* Whh1  = (const float*)d_in[10];
  const float* muW1  = (const float*)d_in[11];
  const float* mub1  = (const float*)d_in[12];
  const float* muW2  = (const float*)d_in[13];
  const float* mub2  = (const float*)d_in[14];
  const float* vaW1  = (const float*)d_in[15];
  const float* vab1  = (const float*)d_in[16];
  const float* vaW2  = (const float*)d_in[17];
  const float* vab2  = (const float*)d_in[18];
  const float* lgW1  = (const float*)d_in[19];
  const float* lgb1  = (const float*)d_in[20];
  const float* lgW2  = (const float*)d_in[21];
  const float* lgb2  = (const float*)d_in[22];
  const float* inith = (const float*)d_in[23];
  const float* initc = (const float*)d_in[24];

  char* wsb = (char*)d_ws;
  unsigned* flags     = (unsigned*)wsb;
  unsigned* counter   = (unsigned*)(wsb + 512);
  float* P            = (float*)(wsb + WS_P);
  float* aee          = (float*)(wsb + WS_AEE);
  unsigned short* vpnsw = (unsigned short*)(wsb + WS_VPN);
  int* eidx           = (int*)(wsb + WS_EIDX);
  unsigned short* corrsw = (unsigned short*)(wsb + WS_CORR);
  unsigned* wq0       = (unsigned*)(wsb + WS_WQ0);
  float* sc0          = (float*)(wsb + WS_SC0);
  unsigned* wqc       = (unsigned*)(wsb + WS_WQC);
  float* scc          = (float*)(wsb + WS_SCC);
  unsigned* h0g       = (unsigned*)(wsb + WS_H0G);
  unsigned* h1w       = (unsigned*)(wsb + WS_H1W);
  unsigned short* h1u = (unsigned short*)(wsb + WS_H1W);

  (void)in_sizes; (void)n_in; (void)ws_size;

  hipMemsetAsync(d_ws, 0, 4096, stream);
  hipMemsetAsync(d_out, 0, (size_t)out_size * 4, stream);

  k_prep_P<<<512, 256, 0, stream>>>(Wih0, ewW2, P);
  k_prep_aee<<<8, 256, 0, stream>>>(Wih0, ee, ewb1, ewb2, P, aee);
  k_prep_vpn<<<LSEQ, 256, 0, stream>>>(Wih0, nemb, aee, vpnsw);
  k_prep_eidx<<<(NB * LSEQ) / 256, 256, 0, stream>>>(x_adj, eidx, counter);
  k_prep_qw<<<1024, 64, 0, stream>>>(Whh0, Wih1, Whh1, wq0, wqc, sc0, scc);
  k_prep_corr<<<NB * LSEQ, 256, 0, stream>>>(x_adj, ewW1, ewb1, P, aee, eidx, corrsw);
  k_lstm<<<2, 1024, 0, stream>>>(wq0, sc0, wqc, scc, (const unsigned*)vpnsw, eidx,
                                 (const unsigned*)corrsw, inith, initc, flags, h0g, h1w);
  k_heads<<<254, 256, 0, stream>>>(h1u, x_adj, lgW1, lgb1, lgW2, lgb2,
                                   muW1, mub1, muW2, mub2, vaW1, vab1, vaW2, vab2,
                                   (float*)d_out);
}